// Round 5
// baseline (89.026 us; speedup 1.0000x reference)
//
#include <hip/hip_runtime.h>
#include <math.h>

#define B_ 8
#define BIGF 3.4e38f

typedef float f32x16 __attribute__((ext_vector_type(16)));

// ws layout (16-B aligned base):
//   packT  : B_*N float4 {x,y,z,|t|^2}
//   packS  : B_*M float4 {x,y,z,|s|^2}
//   minarr : B_*N uint rowmin + B_*M uint colmin (uint-ordered float d^2)

__global__ __launch_bounds__(256) void pack_kernel(
    const float* __restrict__ tar, const float* __restrict__ src,
    float4* __restrict__ packT, float4* __restrict__ packS,
    unsigned int* __restrict__ minarr, float* __restrict__ outp,
    int N, int M)
{
    const int i = blockIdx.x * 256 + threadIdx.x;
    const int nT = B_ * N, nS = B_ * M;
    if (i < nT) {
        float x = tar[3 * i], y = tar[3 * i + 1], z = tar[3 * i + 2];
        packT[i] = make_float4(x, y, z, fmaf(x, x, fmaf(y, y, z * z)));
    } else if (i < nT + nS) {
        int j = i - nT;
        float x = src[3 * j], y = src[3 * j + 1], z = src[3 * j + 2];
        packS[j] = make_float4(x, y, z, fmaf(x, x, fmaf(y, y, z * z)));
    }
    if (i < nT + nS) minarr[i] = 0x7F800000u;  // +inf
    if (i < 3) outp[i] = 0.f;                  // accuracy, complete, chamfer
}

// Load 16 packed refs (256 B) into 64 SGPRs via the scalar cache, then wait.
// Pointer is wave-uniform (blockIdx-derived) -> "s" constraint is natural.
// Latency (~200cy L2) is hidden by TLP (8 waves/SIMD), not by sw pipelining.
#define LOAD_GROUP(A, B, C, D, PTR)                                       \
    asm volatile("s_load_dwordx16 %0, %4, 0x0\n\t"                        \
                 "s_load_dwordx16 %1, %4, 0x40\n\t"                       \
                 "s_load_dwordx16 %2, %4, 0x80\n\t"                       \
                 "s_load_dwordx16 %3, %4, 0xc0\n\t"                       \
                 "s_waitcnt lgkmcnt(0)"                                   \
                 : "=s"(A), "=s"(B), "=s"(C), "=s"(D)                     \
                 : "s"(PTR))

// R5: SGPR-resident refs, zero LDS, 32 waves/CU.
// Evidence trail: R1 (compiler uniform loads) latency-bound 93us; R2
// (readlane) VGPR-starved 41us; R3/R4 (pk_fma) neutral -> v_pk_fma_f32 is
// half-rate on gfx950, instruction packing is a dead end. All rounds ran
// <=16 waves/CU (q-arrays + LDS staging forced VGPR>64) at ~40% issue
// efficiency vs the 12.5us scalar-issue floor. This round: refs live in
// SGPRs (explicit s_load_dwordx16 groups of 16 refs), consumed directly as
// the single allowed SGPR operand of v_fma_f32; |p|^2 pinned to one VGPR
// per ref (amortized over QPT=8 queries). Per-thread state ~55 VGPR ->
// __launch_bounds__(256,8) caps 64 -> 8 blocks/CU co-resident (grid 2048)
// = 32 waves/CU, 4x the TLP of R3/R4. No LDS, no __syncthreads.
// d^2 = |q|^2 + (|p|^2 - 2 q.p): 3 fma/pair + min3/2pairs, |q|^2 added
// after the min (monotone). Cross-block: uint atomicMin (d^2 >= 0).
template <int QPT, int CHUNK>
__global__ __launch_bounds__(256, 8) void minsq_kernel(
    const float4* __restrict__ packT, const float4* __restrict__ packS,
    unsigned int* __restrict__ minarr, int N, int M)
{
    const int z   = blockIdx.z;
    const int dir = (z >= B_) ? 1 : 0;
    const int b   = dir ? (z - B_) : z;
    const float4* __restrict__ qry = dir ? packS : packT;
    const float4* __restrict__ pts = dir ? packT : packS;
    const int K = dir ? M : N;   // query count
    const int L = dir ? N : M;   // reference count
    unsigned int* __restrict__ out =
        minarr + (dir ? (size_t)B_ * N : (size_t)0) + (size_t)b * K;

    const int base = blockIdx.y * CHUNK;
    if (base >= L) return;
    const int cnt = min(CHUNK, L - base);
    const float4* __restrict__ psrc = pts + (size_t)b * L + base;

    const int t = threadIdx.x;
    const int qbase = blockIdx.x * (256 * QPT);
    float qx[QPT], qy[QPT], qz[QPT], qw[QPT], mn[QPT];
#pragma unroll
    for (int k = 0; k < QPT; ++k) {
        int qi = qbase + k * 256 + t;
        if (qi < K) {
            float4 q = qry[(size_t)b * K + qi];
            qx[k] = -2.f * q.x; qy[k] = -2.f * q.y; qz[k] = -2.f * q.z;
            qw[k] = q.w;
        } else {
            qx[k] = 0.f; qy[k] = 0.f; qz[k] = 0.f; qw[k] = 0.f;
        }
        mn[k] = BIGF;
    }

    if (cnt == CHUNK) {
        // Process CHUNK refs in groups of 16 held in 64 SGPRs.
#pragma unroll
        for (int g = 0; g < CHUNK / 16; ++g) {
            f32x16 A, Bv, C, D;
            LOAD_GROUP(A, Bv, C, D, psrc + g * 16);
            // Each f32x16 = 4 refs {x,y,z,w}. Process as 2 ref-pairs per
            // register group so the row-min fuses to v_min3_f32.
#define PAIR(R, i0, i1)                                                   \
            {                                                             \
                float s0x = R[4*(i0)+0], s0y = R[4*(i0)+1],               \
                      s0z = R[4*(i0)+2], v0w = R[4*(i0)+3];               \
                float s1x = R[4*(i1)+0], s1y = R[4*(i1)+1],               \
                      s1z = R[4*(i1)+2], v1w = R[4*(i1)+3];               \
                asm("" : "+v"(v0w));  /* pin addend to VGPR, 1 mov/ref */ \
                asm("" : "+v"(v1w));                                      \
                _Pragma("unroll")                                         \
                for (int k = 0; k < QPT; ++k) {                           \
                    float d0 = fmaf(qx[k], s0x, fmaf(qy[k], s0y,          \
                               fmaf(qz[k], s0z, v0w)));                   \
                    float d1 = fmaf(qx[k], s1x, fmaf(qy[k], s1y,          \
                               fmaf(qz[k], s1z, v1w)));                   \
                    mn[k] = fminf(fminf(d0, d1), mn[k]); /* v_min3 */     \
                }                                                         \
            }
            PAIR(A, 0, 1)  PAIR(A, 2, 3)
            PAIR(Bv, 0, 1) PAIR(Bv, 2, 3)
            PAIR(C, 0, 1)  PAIR(C, 2, 3)
            PAIR(D, 0, 1)  PAIR(D, 2, 3)
#undef PAIR
        }
    } else {
        // Generic tail (never taken for N=M=4096; kept for correctness).
        for (int j = 0; j < cnt; ++j) {
            float4 p0 = psrc[j];
#pragma unroll
            for (int k = 0; k < QPT; ++k) {
                float d0 = fmaf(qx[k], p0.x, fmaf(qy[k], p0.y,
                           fmaf(qz[k], p0.z, p0.w)));
                mn[k] = fminf(mn[k], d0);
            }
        }
    }

#pragma unroll
    for (int k = 0; k < QPT; ++k) {
        int qi = qbase + k * 256 + t;
        if (qi < K) {
            float d2 = fmaxf(mn[k] + qw[k], 0.f);  // clamp roundoff negatives
            atomicMin(&out[qi], __float_as_uint(d2));
        }
    }
}

// Merged reduce+finalize: 32 blocks stripe-sum sqrt of both regions, then 3
// scaled atomicAdds into d_out (zeroed by pack_kernel).
__global__ __launch_bounds__(256) void reduce_kernel(
    const unsigned int* __restrict__ minarr, float* __restrict__ outp,
    int N, int M)
{
    const int nt = B_ * N, ns = B_ * M;
    const int gid = blockIdx.x * 256 + threadIdx.x;
    const int stride = gridDim.x * 256;
    float s_t = 0.f, s_s = 0.f;
    for (int i = gid; i < nt; i += stride)
        s_t += sqrtf(__uint_as_float(minarr[i]));
    for (int i = gid; i < ns; i += stride)
        s_s += sqrtf(__uint_as_float(minarr[nt + i]));
#pragma unroll
    for (int off = 32; off > 0; off >>= 1) {
        s_t += __shfl_down(s_t, off);
        s_s += __shfl_down(s_s, off);
    }
    __shared__ float rt[4], rs[4];
    const int wid = threadIdx.x >> 6, lid = threadIdx.x & 63;
    if (lid == 0) { rt[wid] = s_t; rs[wid] = s_s; }
    __syncthreads();
    if (threadIdx.x == 0) {
        float ct = (rt[0] + rt[1] + rt[2] + rt[3]) / (float)nt;  // complete
        float ac = (rs[0] + rs[1] + rs[2] + rs[3]) / (float)ns;  // accuracy
        atomicAdd(&outp[0], ac);
        atomicAdd(&outp[1], ct);
        atomicAdd(&outp[2], 0.5f * (ac + ct));
    }
}

extern "C" void kernel_launch(void* const* d_in, const int* in_sizes, int n_in,
                              void* d_out, int out_size, void* d_ws, size_t ws_size,
                              hipStream_t stream) {
    const float* tar = (const float*)d_in[0];
    const float* src = (const float*)d_in[1];
    const int N = in_sizes[0] / (B_ * 3);
    const int M = in_sizes[1] / (B_ * 3);

    float4* packT = (float4*)d_ws;
    float4* packS = packT + (size_t)B_ * N;
    unsigned int* minarr = (unsigned int*)(packS + (size_t)B_ * M);
    float* outp = (float*)d_out;

    pack_kernel<<<dim3((B_ * (N + M) + 255) / 256), dim3(256), 0, stream>>>(
        tar, src, packT, packS, minarr, outp, N, M);

    constexpr int QPT = 8, CHUNK = 64;
    const int KL = (N > M) ? N : M;
    const int gx = (KL + 256 * QPT - 1) / (256 * QPT);   // 2
    const int gy = (KL + CHUNK - 1) / CHUNK;             // 64
    dim3 grid(gx, gy, 2 * B_);                            // 2048 blocks
    minsq_kernel<QPT, CHUNK><<<grid, dim3(256), 0, stream>>>(
        packT, packS, minarr, N, M);

    reduce_kernel<<<dim3(32), dim3(256), 0, stream>>>(minarr, outp, N, M);
}

// Round 6
// 84.763 us; speedup vs baseline: 1.0503x; 1.0503x over previous
//
#include <hip/hip_runtime.h>
#include <math.h>

#define B_ 8
#define BIGF 3.4e38f

// ws layout: minarr only now:
//   minarr : B_*N uint rowmin (per-target min d^2, uint-ordered floats)
//            followed by B_*M uint colmin (per-source min d^2)
// Init to 0xFFFFFFFF by hipMemsetAsync (valid "+inf" for uint ordering:
// every clamped d^2 bit pattern is smaller). d_out zeroed by memset too.
//
// R6 = R0 (best measured, 84.5us) + two surgical changes:
//  (a) pack_kernel deleted: |p|^2 / |q|^2 folded into minsq staging/prologue
//      with BITWISE-IDENTICAL fma expressions (absmax stayed 0.0 across all
//      rounds with this formula); init via 2 hipMemsetAsync graph nodes.
//      Saves one dispatch + gap + the packed-array round trip.
//  (b) explicit 2-deep software pipeline on the LDS broadcast reads:
//      load sp[j+2],sp[j+3] into registers BEFORE computing on sp[j],sp[j+1]
//      so the ~120cy ds_read latency is covered by the 112cy VALU block.
//      Theory: R0's 28us vs the 12.5us issue floor == (120+112)/112 = 2.1x
//      exposed-latency ratio; every non-LDS variant (scalar k$ R1, readlane
//      R2, pk_fma R3/R4, SMEM R5) was neutral-or-worse, so the instruction
//      mix stays R0's: 3 v_fma + 0.5 v_min3 per pair, LDS wave-uniform
//      broadcast b128 for refs.
// Cross-block combine: distributed uint atomicMin (d^2 clamped >= 0 so uint
// order == float order).
template <int QPT, int CHUNK>
__global__ __launch_bounds__(256, 4) void minsq_kernel(
    const float* __restrict__ tar, const float* __restrict__ src,
    unsigned int* __restrict__ minarr, int N, int M)
{
    const int z   = blockIdx.z;
    const int dir = (z >= B_) ? 1 : 0;
    const int b   = dir ? (z - B_) : z;
    const float* __restrict__ qry = dir ? src : tar;   // raw float3 streams
    const float* __restrict__ pts = dir ? tar : src;
    const int K = dir ? M : N;   // query count
    const int L = dir ? N : M;   // reference count
    unsigned int* __restrict__ out =
        minarr + (dir ? (size_t)B_ * N : (size_t)0) + (size_t)b * K;

    const int base = blockIdx.y * CHUNK;
    if (base >= L) return;
    const int cnt = min(CHUNK, L - base);

    // Stage refs as float4 {x,y,z,|p|^2} (same fma form the old pack used).
    __shared__ float4 sp[CHUNK];
    const float* __restrict__ p3 = pts + ((size_t)b * L + base) * 3;
    const int t = threadIdx.x;
    for (int i = t; i < cnt; i += 256) {
        float x = p3[3 * i], y = p3[3 * i + 1], zc = p3[3 * i + 2];
        sp[i] = make_float4(x, y, zc, fmaf(x, x, fmaf(y, y, zc * zc)));
    }
    __syncthreads();

    const float* __restrict__ q3 = qry + (size_t)b * K * 3;
    const int qbase = blockIdx.x * (256 * QPT);
    float qx2[QPT], qy2[QPT], qz2[QPT], qw[QPT], mn[QPT];
#pragma unroll
    for (int k = 0; k < QPT; ++k) {
        int qi = qbase + k * 256 + t;
        if (qi < K) {
            float x = q3[3 * qi], y = q3[3 * qi + 1], zc = q3[3 * qi + 2];
            qx2[k] = -2.f * x; qy2[k] = -2.f * y; qz2[k] = -2.f * zc;
            qw[k] = fmaf(x, x, fmaf(y, y, zc * zc));
        } else {
            qx2[k] = 0.f; qy2[k] = 0.f; qz2[k] = 0.f; qw[k] = 0.f;
        }
        mn[k] = BIGF;
    }

    if (cnt == CHUNK) {
        // 2-deep software pipeline: prefetch next ref pair while computing
        // on the current one; lgkmcnt wait lands after 112cy of VALU.
        float4 c0 = sp[0], c1 = sp[1];
#pragma unroll 2
        for (int j = 0; j + 2 < CHUNK; j += 2) {
            float4 n0 = sp[j + 2];
            float4 n1 = sp[j + 3];
#pragma unroll
            for (int k = 0; k < QPT; ++k) {
                float d0 = fmaf(qx2[k], c0.x, fmaf(qy2[k], c0.y,
                           fmaf(qz2[k], c0.z, c0.w)));
                float d1 = fmaf(qx2[k], c1.x, fmaf(qy2[k], c1.y,
                           fmaf(qz2[k], c1.z, c1.w)));
                mn[k] = fminf(mn[k], fminf(d0, d1));   // v_min3_f32
            }
            c0 = n0; c1 = n1;
        }
        // epilogue pair (126,127)
#pragma unroll
        for (int k = 0; k < QPT; ++k) {
            float d0 = fmaf(qx2[k], c0.x, fmaf(qy2[k], c0.y,
                       fmaf(qz2[k], c0.z, c0.w)));
            float d1 = fmaf(qx2[k], c1.x, fmaf(qy2[k], c1.y,
                       fmaf(qz2[k], c1.z, c1.w)));
            mn[k] = fminf(mn[k], fminf(d0, d1));
        }
    } else {
        // Generic tail (never taken for N=M=4096; kept for correctness).
        int j = 0;
        for (; j + 1 < cnt; j += 2) {
            float4 p0 = sp[j];
            float4 p1 = sp[j + 1];
#pragma unroll
            for (int k = 0; k < QPT; ++k) {
                float d0 = fmaf(qx2[k], p0.x, fmaf(qy2[k], p0.y,
                           fmaf(qz2[k], p0.z, p0.w)));
                float d1 = fmaf(qx2[k], p1.x, fmaf(qy2[k], p1.y,
                           fmaf(qz2[k], p1.z, p1.w)));
                mn[k] = fminf(mn[k], fminf(d0, d1));
            }
        }
        if (j < cnt) {
            float4 p0 = sp[j];
#pragma unroll
            for (int k = 0; k < QPT; ++k) {
                float d0 = fmaf(qx2[k], p0.x, fmaf(qy2[k], p0.y,
                           fmaf(qz2[k], p0.z, p0.w)));
                mn[k] = fminf(mn[k], d0);
            }
        }
    }

#pragma unroll
    for (int k = 0; k < QPT; ++k) {
        int qi = qbase + k * 256 + t;
        if (qi < K) {
            float d2 = fmaxf(mn[k] + qw[k], 0.f);  // clamp roundoff negatives
            atomicMin(&out[qi], __float_as_uint(d2));
        }
    }
}

// Merged reduce+finalize: 32 blocks stripe-sum sqrt of both regions, then 3
// scaled atomicAdds into d_out (zeroed by memset node). 96 same-line atomics
// ~1.4 us — cheaper than a second reduce node.
__global__ __launch_bounds__(256) void reduce_kernel(
    const unsigned int* __restrict__ minarr, float* __restrict__ outp,
    int N, int M)
{
    const int nt = B_ * N, ns = B_ * M;
    const int gid = blockIdx.x * 256 + threadIdx.x;
    const int stride = gridDim.x * 256;
    float s_t = 0.f, s_s = 0.f;
    for (int i = gid; i < nt; i += stride)
        s_t += sqrtf(__uint_as_float(minarr[i]));
    for (int i = gid; i < ns; i += stride)
        s_s += sqrtf(__uint_as_float(minarr[nt + i]));
#pragma unroll
    for (int off = 32; off > 0; off >>= 1) {
        s_t += __shfl_down(s_t, off);
        s_s += __shfl_down(s_s, off);
    }
    __shared__ float rt[4], rs[4];
    const int wid = threadIdx.x >> 6, lid = threadIdx.x & 63;
    if (lid == 0) { rt[wid] = s_t; rs[wid] = s_s; }
    __syncthreads();
    if (threadIdx.x == 0) {
        float ct = (rt[0] + rt[1] + rt[2] + rt[3]) / (float)nt;  // complete
        float ac = (rs[0] + rs[1] + rs[2] + rs[3]) / (float)ns;  // accuracy
        atomicAdd(&outp[0], ac);
        atomicAdd(&outp[1], ct);
        atomicAdd(&outp[2], 0.5f * (ac + ct));
    }
}

extern "C" void kernel_launch(void* const* d_in, const int* in_sizes, int n_in,
                              void* d_out, int out_size, void* d_ws, size_t ws_size,
                              hipStream_t stream) {
    const float* tar = (const float*)d_in[0];
    const float* src = (const float*)d_in[1];
    const int N = in_sizes[0] / (B_ * 3);
    const int M = in_sizes[1] / (B_ * 3);

    unsigned int* minarr = (unsigned int*)d_ws;
    float* outp = (float*)d_out;

    // Graph-capturable memset nodes: minarr -> 0xFFFFFFFF (uint +inf for
    // atomicMin ordering), outp -> 0 (accumulated by reduce's atomicAdd).
    hipMemsetAsync(minarr, 0xFF, (size_t)B_ * (N + M) * sizeof(unsigned int),
                   stream);
    hipMemsetAsync(outp, 0, 3 * sizeof(float), stream);

    constexpr int QPT = 8, CHUNK = 128;
    const int KL = (N > M) ? N : M;
    const int gx = (KL + 256 * QPT - 1) / (256 * QPT);   // 2
    const int gy = (KL + CHUNK - 1) / CHUNK;             // 32
    dim3 grid(gx, gy, 2 * B_);                            // 1024 blocks
    minsq_kernel<QPT, CHUNK><<<grid, dim3(256), 0, stream>>>(
        tar, src, minarr, N, M);

    reduce_kernel<<<dim3(32), dim3(256), 0, stream>>>(minarr, outp, N, M);
}